// Round 14
// baseline (117.474 us; speedup 1.0000x reference)
//
#include <hip/hip_runtime.h>
#include <hip/hip_bf16.h>

#define HH 8
#define DKK 32
#define DM 256
#define NN 512
#define DE 40
#define DHID 32
#define CH 128

typedef __attribute__((ext_vector_type(4))) short short4v;
typedef __attribute__((ext_vector_type(8))) short short8v;
typedef __attribute__((ext_vector_type(4))) float f32x4;

__device__ __forceinline__ unsigned short f2bf(float x) {
    union { __hip_bfloat16 h; unsigned short u; } c;
    c.h = __float2bfloat16(x);
    return c.u;
}
__device__ __forceinline__ float bf2f(unsigned short u) {
    return __uint_as_float(((unsigned int)u) << 16);
}
__device__ __forceinline__ unsigned int pack2bf(float a, float b) {
    return (unsigned int)f2bf(a) | ((unsigned int)f2bf(b) << 16);
}
__device__ __forceinline__ short8v ld8(const unsigned short* p) {
    short4v lo = *(const short4v*)p;
    short4v hi = *(const short4v*)(p + 4);
    short8v r;
    r[0]=lo[0]; r[1]=lo[1]; r[2]=lo[2]; r[3]=lo[3];
    r[4]=hi[0]; r[5]=hi[1]; r[6]=hi[2]; r[7]=hi[3];
    return r;
}

// ---------------- projection; q also emitted as (q*inv) bf16, K as bf16 row-major ----------------
__global__ __launch_bounds__(256) void proj_kernel(
    const float* __restrict__ query, const float* __restrict__ key_,
    const float* __restrict__ value,
    const float* __restrict__ Wq, const float* __restrict__ bq,
    const float* __restrict__ Wk, const float* __restrict__ bk,
    const float* __restrict__ Wv, const float* __restrict__ bv,
    float* __restrict__ Q, float* __restrict__ K, float* __restrict__ V,
    unsigned short* __restrict__ qbf, unsigned short* __restrict__ Kbf,
    int grpPerMat)
{
    const int m  = blockIdx.x / grpPerMat;          // 0=q 1=k 2=v
    const int r0 = (blockIdx.x % grpPerMat) * 4;
    const float* x; const float* W; const float* bb; float* dst;
    if (m == 0)      { x = query; W = Wq; bb = bq; dst = Q; }
    else if (m == 1) { x = key_;  W = Wk; bb = bk; dst = K; }
    else             { x = value; W = Wv; bb = bv; dst = V; }
    const int c = threadIdx.x;
    const float b0 = bb[c];
    float a0 = b0, a1 = b0, a2 = b0, a3 = b0;
    for (int k = 0; k < DM; ++k) {
        const float w = W[k*DM + c];
        a0 = fmaf(x[(size_t)(r0+0)*DM + k], w, a0);   // uniform x -> scalar loads
        a1 = fmaf(x[(size_t)(r0+1)*DM + k], w, a1);
        a2 = fmaf(x[(size_t)(r0+2)*DM + k], w, a2);
        a3 = fmaf(x[(size_t)(r0+3)*DM + k], w, a3);
    }
    dst[(size_t)(r0+0)*DM + c] = a0;
    dst[(size_t)(r0+1)*DM + c] = a1;
    dst[(size_t)(r0+2)*DM + c] = a2;
    dst[(size_t)(r0+3)*DM + c] = a3;
    if (m == 0) {
        const float inv = 0.17677669529663687f;
        qbf[(size_t)(r0+0)*DM + c] = f2bf(a0*inv);
        qbf[(size_t)(r0+1)*DM + c] = f2bf(a1*inv);
        qbf[(size_t)(r0+2)*DM + c] = f2bf(a2*inv);
        qbf[(size_t)(r0+3)*DM + c] = f2bf(a3*inv);
    } else if (m == 1) {
        Kbf[(size_t)(r0+0)*DM + c] = f2bf(a0);
        Kbf[(size_t)(r0+1)*DM + c] = f2bf(a1);
        Kbf[(size_t)(r0+2)*DM + c] = f2bf(a2);
        Kbf[(size_t)(r0+3)*DM + c] = f2bf(a3);
    }
}

// ---------------- pre: prep rows (0..1023) + w1 build (1024) ----------------
__global__ __launch_bounds__(256) void pre_kernel(
    const float* __restrict__ Q, const float* __restrict__ K,
    const float* __restrict__ vvec,
    const float* __restrict__ rkW2, const float* __restrict__ rkb2,
    const float* __restrict__ rkW1, const float* __restrict__ rvW1,
    const float* __restrict__ rkb1, const float* __restrict__ rvb1,
    float* __restrict__ gkw, unsigned short* __restrict__ w1w,
    float* __restrict__ biasw, int rows)
{
    const int bid = blockIdx.x;
    const int tid = threadIdx.x;
    if (bid < rows) {
        // gK[h,t] (bf16) + c0K[h] per row
        const int bi = bid;
        const int h = tid >> 5, l32 = tid & 31;
        const float inv = 0.17677669529663687f;
        __shared__ __align__(16) float wf[DM];
        wf[tid] = inv*(Q[(size_t)bi*DM + tid] + K[(size_t)bi*DM + tid]) + vvec[tid];
        __syncthreads();
        float acc = 0.f;
#pragma unroll
        for (int d4 = 0; d4 < DKK/4; ++d4) {
            const float4 w4 = *(const float4*)(rkW2 + (size_t)l32*DM + h*DKK + d4*4);
            const float4 f4 = *(const float4*)(&wf[h*DKK + d4*4]);
            acc = fmaf(w4.x, f4.x, acc); acc = fmaf(w4.y, f4.y, acc);
            acc = fmaf(w4.z, f4.z, acc); acc = fmaf(w4.w, f4.w, acc);
        }
        ((unsigned short*)(gkw + (size_t)bi*264))[tid] = f2bf(acc);   // gkbf[h*32+t]
        if (tid < HH) {
            float a2 = 0.f;
#pragma unroll
            for (int d = 0; d < DKK; ++d)
                a2 = fmaf(rkb2[tid*DKK + d], wf[tid*DKK + d], a2);
            gkw[(size_t)bi*264 + 256 + tid] = a2;                     // c0K
        }
    } else {
        // w1: combined W1k|W1v bf16 [64][68] + bias[64]
        const int n = tid >> 2, qd = tid & 3;
#pragma unroll
        for (int kk = 0; kk < 17; ++kk) {
            const int k = qd*17 + kk;
            float v = 0.f;
            if (k < DE) v = (n < 32) ? rkW1[k*DHID + n] : rvW1[k*DHID + (n-32)];
            w1w[n*68 + k] = f2bf(v);
        }
        if (tid < 64) biasw[tid] = (tid < 32) ? rkb1[tid] : rvb1[tid-32];
    }
}

// ---------------- chunk kernel: ONE 128-j chunk per block. grid = rows*4 ----------------
// MFMA for MLP layer-1, scores (s1+s2 fused), accA. Scalar coalesced accO.
__global__ __launch_bounds__(256, 6) void chunk_kernel(
    const float* __restrict__ edges, const int* __restrict__ mask,
    const float* __restrict__ V,
    const unsigned short* __restrict__ qbf, const unsigned short* __restrict__ Kbf,
    const unsigned short* __restrict__ w1w, const float* __restrict__ biasw,
    const float* __restrict__ gkw,
    float* __restrict__ ws_m, float* __restrict__ ws_z,
    float* __restrict__ ws_A, float* __restrict__ ws_O)
{
    const int bid = blockIdx.x;
    const int bi = bid >> 2, cq = bid & 3;   // row, j-quarter
    const int b  = bi >> 9;
    const int i  = bi & 511;
    const int j0 = cq*CH;
    const int tid = threadIdx.x;
    const int h = tid >> 5, l32 = tid & 31;          // softmax mapping
    const int wid = tid >> 6, lane = tid & 63;       // wave mapping (mfma)
    const int g = lane >> 4, q16 = lane & 15;
    const int team = tid >> 6, qq = tid & 63, hq = qq >> 3;  // accO mapping
    const int jj = tid & 127, half = tid >> 7;       // E-load mapping

    // ---- LDS ----
    __shared__ __align__(16) unsigned char uni[18816];
    __shared__ __align__(16) float sc[HH*132];
    __shared__ __align__(16) unsigned short gkb_l[16*32];   // gK^T bf16, rows 8..15 zero
    __shared__ int mask_l[CH];
    __shared__ float c0Ks[HH];

    unsigned short* E   = (unsigned short*)uni;              // [128][68] bf16
    unsigned short* hvT = (unsigned short*)uni;              // [32][132] bf16 (overlays E)
    unsigned short* hk  = (unsigned short*)(uni + 8448);     // [128][40] bf16
    unsigned short* pb  = (unsigned short*)(uni + 8448);     // [8][132] bf16 (overlays hk)
    float* paccA = (float*)uni;                              // [4][256] epilogue
    float* po    = (float*)(uni + 4096);                     // [4][256] epilogue

    const size_t ebase = (size_t)b*DE*NN*NN + (size_t)i*NN;

    // ---- prefetch this chunk's edges into regs ----
    float ev[20];
    {
        const float* ep = edges + ebase + j0 + jj;
#pragma unroll
        for (int u = 0; u < 20; ++u) ev[u] = ep[(size_t)(half*20+u)*NN*NN];
    }

    // ---- prologue staging ----
    {
        // gkb: rows 0..7 copy, 8..15 zero (dword granularity: 256 dwords)
        const unsigned int* gsrc = (const unsigned int*)(gkw + (size_t)bi*264);
        unsigned int* gdst = (unsigned int*)gkb_l;
        gdst[tid] = (tid < 128) ? gsrc[tid] : 0u;
        if (tid < CH) mask_l[tid] = mask[b*NN + j0 + tid];
        if (tid < HH) c0Ks[tid] = gkw[(size_t)bi*264 + 256 + tid];
    }
    // myq: lane q16<8 holds q*inv slice for head q16 at k-offset g*8
    short8v z8 = {0,0,0,0,0,0,0,0};
    short8v myq = z8;
    if (q16 < HH) myq = ld8(&qbf[(size_t)bi*DM + q16*DKK + g*8]);
    float biasv[4];
#pragma unroll
    for (int nt = 0; nt < 4; ++nt) biasv[nt] = biasw[nt*16 + q16];

    // ---- pack prefetched edges -> bf16 LDS [128][68] (cols 40..63 zero) ----
    {
        unsigned int* Ed = (unsigned int*)&E[jj*68 + half*20];
#pragma unroll
        for (int u = 0; u < 10; ++u) Ed[u] = pack2bf(ev[2*u], ev[2*u+1]);
        if (half) {
            unsigned int* Ez = (unsigned int*)&E[jj*68 + 40];
#pragma unroll
            for (int z = 0; z < 12; ++z) Ez[z] = 0u;
        }
    }
    __syncthreads();   // B1: E + staging ready

    // ---- h1 = E @ W1 (+bias) via MFMA; W1 fragments direct from global ----
    f32x4 acc[2][4];
#pragma unroll
    for (int jt = 0; jt < 2; ++jt) {
        const int jn = wid*32 + jt*16 + q16;
        short8v a0 = ld8(&E[jn*68 + g*8]);
        short8v a1 = ld8(&E[jn*68 + 32 + g*8]);
#pragma unroll
        for (int nt = 0; nt < 4; ++nt) {
            const unsigned short* wp = w1w + (q16 + nt*16)*68 + g*8;
            f32x4 c;
            c[0] = biasv[nt]; c[1] = biasv[nt]; c[2] = biasv[nt]; c[3] = biasv[nt];
            c = __builtin_amdgcn_mfma_f32_16x16x32_bf16(a0, ld8(wp), c, 0, 0, 0);
            c = __builtin_amdgcn_mfma_f32_16x16x32_bf16(a1, ld8(wp + 32), c, 0, 0, 0);
            acc[jt][nt] = c;
        }
    }
    __syncthreads();   // B2: all E reads done before overwrite

    // ---- leaky + writeback: hk[j][t] (stride 40) and hvT[t][j] ----
#pragma unroll
    for (int jt = 0; jt < 2; ++jt) {
        const int jw = wid*32 + jt*16 + g*4;
#pragma unroll
        for (int nt = 0; nt < 4; ++nt) {
#pragma unroll
            for (int r = 0; r < 4; ++r) {
                float x = acc[jt][nt][r];
                x = x > 0.f ? x : 0.1f*x;
                const unsigned short us = f2bf(x);
                const int n = nt*16 + q16;
                if (n < 32) hk[(jw+r)*40 + n] = us;
                else        hvT[(n-32)*132 + (jw+r)] = us;
            }
        }
    }
    __syncthreads();   // B3: hk/hvT ready

    // ---- scores via MFMA: D[j][h] = c0K + sum_h K.q (block-diag) + hk.gK^T ----
    {
        const unsigned short* kbase = Kbf + ((size_t)(b*NN + j0))*DM;
        short8v gkB = ld8(&gkb_l[q16*DKK + g*8]);
#pragma unroll
        for (int jt = 0; jt < 2; ++jt) {
            const int jrow = wid*32 + jt*16 + q16;
            const float ci = (q16 < HH) ? c0Ks[q16 & 7] : 0.f;
            f32x4 s;
            s[0] = ci; s[1] = ci; s[2] = ci; s[3] = ci;
#pragma unroll
            for (int hh = 0; hh < HH; ++hh) {
                short8v aK = ld8(&kbase[(size_t)jrow*DM + hh*DKK + g*8]);
                short8v bq = (q16 == hh) ? myq : z8;
                s = __builtin_amdgcn_mfma_f32_16x16x32_bf16(aK, bq, s, 0, 0, 0);
            }
            short8v aH = ld8(&hk[jrow*40 + g*8]);
            s = __builtin_amdgcn_mfma_f32_16x16x32_bf16(aH, gkB, s, 0, 0, 0);
            if (q16 < HH) {
#pragma unroll
                for (int r = 0; r < 4; ++r) {
                    const int jl = wid*32 + jt*16 + g*4 + r;
                    float v = s[r];
                    if (mask_l[jl] == 0) v = -1e12f;
                    sc[q16*132 + jl] = v;
                }
            }
        }
    }
    __syncthreads();   // B4: sc ready (hk reads done)

    // ---- local softmax (head h per 32-lane group), publish p bf16, emit m/Z ----
    {
        float sv[4];
        float mc = -3e38f;
#pragma unroll
        for (int k = 0; k < 4; ++k) { sv[k] = sc[h*132 + l32 + 32*k]; mc = fmaxf(mc, sv[k]); }
#pragma unroll
        for (int off = 16; off; off >>= 1) mc = fmaxf(mc, __shfl_xor(mc, off, 32));
        float zc = 0.f;
#pragma unroll
        for (int k = 0; k < 4; ++k) {
            const float e = __expf(sv[k] - mc);
            pb[h*132 + l32 + 32*k] = f2bf(e);
            zc += e;
        }
#pragma unroll
        for (int off = 16; off; off >>= 1) zc += __shfl_xor(zc, off, 32);
        if (l32 == 0) {
            ws_m[(size_t)bid*8 + h] = mc;
            ws_z[(size_t)bid*8 + h] = zc;
        }
    }
    __syncthreads();   // B5: pb visible

    // ---- accA via MFMA (wave = K-quarter) ----
    f32x4 ca0 = {0.f,0.f,0.f,0.f}, ca1 = {0.f,0.f,0.f,0.f};
    {
        short8v pA = ld8(&pb[q16*132 + wid*32 + g*8]);
        short8v b0 = ld8(&hvT[q16*132 + wid*32 + g*8]);
        short8v b1 = ld8(&hvT[(16+q16)*132 + wid*32 + g*8]);
        ca0 = __builtin_amdgcn_mfma_f32_16x16x32_bf16(pA, b0, ca0, 0, 0, 0);
        ca1 = __builtin_amdgcn_mfma_f32_16x16x32_bf16(pA, b1, ca1, 0, 0, 0);
    }
    // ---- accO: coalesced scalar loop (channels qq*4..+3, j = j0 + team + 4*it) ----
    float aO0 = 0.f, aO1 = 0.f, aO2 = 0.f, aO3 = 0.f;
    {
        const float* vrow = V + (size_t)b*NN*DM + (size_t)(j0 + team)*DM + qq*4;
        const unsigned short* ph = pb + hq*132 + team;
#pragma unroll 4
        for (int it = 0; it < 32; ++it) {
            const float p = bf2f(ph[4*it]);
            const float4 v4 = *(const float4*)(vrow + (size_t)it*4*DM);
            aO0 = fmaf(p, v4.x, aO0); aO1 = fmaf(p, v4.y, aO1);
            aO2 = fmaf(p, v4.z, aO2); aO3 = fmaf(p, v4.w, aO3);
        }
    }
    __syncthreads();   // B6: pb/hvT consumed; epilogue overlays uni

    // ---- epilogue: reduce wave partials, emit raw (A, O) ----
    if (g < 2) {
#pragma unroll
        for (int r = 0; r < 4; ++r) {
            const int hrow = g*4 + r;
            paccA[wid*256 + hrow*32 + q16]      = ca0[r];
            paccA[wid*256 + hrow*32 + 16 + q16] = ca1[r];
        }
    }
    *(float4*)(po + team*256 + qq*4) = make_float4(aO0, aO1, aO2, aO3);
    __syncthreads();   // B7

    ws_A[(size_t)bid*256 + tid] = paccA[tid] + paccA[256+tid] + paccA[512+tid] + paccA[768+tid];
    ws_O[(size_t)bid*256 + tid] = po[tid] + po[256+tid] + po[512+tid] + po[768+tid];
}

// ---------------- combine: 4-way flash merge, o2, Wo epilogue. 2 rows per block ----------------
__global__ __launch_bounds__(256) void combine_kernel(
    const float* __restrict__ rvW2, const float* __restrict__ rvb2,
    const float* __restrict__ Wo, const float* __restrict__ bo,
    const float* __restrict__ ws_m, const float* __restrict__ ws_z,
    const float* __restrict__ ws_A, const float* __restrict__ ws_O,
    float* __restrict__ out)
{
    const int bi0 = blockIdx.x * 2;
    const int tid = threadIdx.x;
    const int h = tid >> 5;
    __shared__ float A_l[2][DM], o_l[2][DM];
    __shared__ float wqs[2][4][HH], rzs[2][HH];

    if (tid < 16) {
        const int r = tid >> 3, hh = tid & 7;
        const int bi = bi0 + r;
        float mv[4], zv[4];
#pragma unroll
        for (int q = 0; q < 4; ++q) {
            mv[q] = ws_m[(size_t)(bi*4+q)*8 + hh];
            zv[q] = ws_z[(size_t)(bi*4+q)*8 + hh];
        }
        const float mm = fmaxf(fmaxf(mv[0], mv[1]), fmaxf(mv[2], mv[3]));
        float zt = 0.f;
#pragma unroll
        for (int q = 0; q < 4; ++q) {
            const float w = __expf(mv[q] - mm);
            wqs[r][q][hh] = w;
            zt = fmaf(zv[q], w, zt);
        }
        rzs[r][hh] = 1.f / zt;
    }
    __syncthreads();

    float o1v[2];
#pragma unroll
    for (int r = 0; r < 2; ++r) {
        const int bi = bi0 + r;
        const float rz = rzs[r][h];
        float A = 0.f, o1 = 0.f;
#pragma unroll
        for (int q = 0; q < 4; ++q) {
            const float w = wqs[r][q][h];
            A  = fmaf(w, ws_A[(size_t)(bi*4+q)*256 + tid], A);
            o1 = fmaf(w, ws_O[(size_t)(bi*4+q)*256 + tid], o1);
        }
        A_l[r][tid] = A * rz;
        o1v[r] = o1 * rz;
    }
    __syncthreads();

#pragma unroll
    for (int r = 0; r < 2; ++r) {
        float o2 = rvb2[tid];
#pragma unroll
        for (int t = 0; t < DHID; ++t)
            o2 = fmaf(A_l[r][h*DKK + t], rvW2[(size_t)t*DM + tid], o2);
        o_l[r][tid] = o1v[r] + o2;
    }
    __syncthreads();

    float acc0 = bo[tid], acc1 = acc0;
#pragma unroll 4
    for (int k = 0; k < DM; ++k) {
        const float w = Wo[(size_t)k*DM + tid];
        acc0 = fmaf(o_l[0][k], w, acc0);
        acc1 = fmaf(o_l[1][k], w, acc1);
    }
    out[(size_t)(bi0+0)*DM + tid] = acc0;
    out[(size_t)(bi0+1)*DM + tid] = acc1;
}

extern "C" void kernel_launch(void* const* d_in, const int* in_sizes, int n_in,
                              void* d_out, int out_size, void* d_ws, size_t ws_size,
                              hipStream_t stream) {
    const float* query = (const float*)d_in[0];
    const float* key_  = (const float*)d_in[1];
    const float* value = (const float*)d_in[2];
    const float* edges = (const float*)d_in[3];
    const int*   mask  = (const int*)d_in[4];
    const float* Wq = (const float*)d_in[5];
    const float* bq = (const float*)d_in[6];
    const float* Wk = (const float*)d_in[7];
    const float* bk = (const float*)d_in[8];
    const float* Wv = (const float*)d_in[9];
    const float* bv = (const float*)d_in[10];
    const float* Wo = (const float*)d_in[11];
    const float* bo = (const float*)d_in[12];
    const float* rkW1 = (const float*)d_in[13];
    const float* rkb1 = (const float*)d_in[14];
    const float* rkW2 = (const float*)d_in[15];
    const float* rkb2 = (const float*)d_in[16];
    const float* rvW1 = (const float*)d_in[17];
    const float* rvb1 = (const float*)d_in[18];
    const float* rvW2 = (const float*)d_in[19];
    const float* rvb2 = (const float*)d_in[20];
    // d_in[21] (u) is softmax-invariant -> unused
    const float* vvec = (const float*)d_in[22];

    const int rows = in_sizes[0] / DM;   // b*n = 1024
    const int nchunk = rows * 4;         // 4096

    float* Qw   = (float*)d_ws;
    float* Kw   = Qw + (size_t)rows*DM;
    float* Vw   = Kw + (size_t)rows*DM;
    float* gkw  = Vw + (size_t)rows*DM;                       // rows*264
    float* biasw = gkw + (size_t)rows*264;                    // 64
    float* ws_m = biasw + 64;
    float* ws_z = ws_m + (size_t)nchunk*8;
    float* ws_A = ws_z + (size_t)nchunk*8;
    float* ws_O = ws_A + (size_t)nchunk*256;
    unsigned short* qbf = (unsigned short*)(ws_O + (size_t)nchunk*256);  // rows*256
    unsigned short* Kbf = qbf + (size_t)rows*DM;              // rows*256
    unsigned short* w1w = Kbf + (size_t)rows*DM;              // 64*68

    hipLaunchKernelGGL(proj_kernel, dim3(3*rows/4), dim3(256), 0, stream,
                       query, key_, value, Wq, bq, Wk, bk, Wv, bv,
                       Qw, Kw, Vw, qbf, Kbf, rows/4);
    hipLaunchKernelGGL(pre_kernel, dim3(rows + 1), dim3(256), 0, stream,
                       Qw, Kw, vvec, rkW2, rkb2, rkW1, rvW1, rkb1, rvb1,
                       gkw, w1w, biasw, rows);
    hipLaunchKernelGGL(chunk_kernel, dim3(nchunk), dim3(256), 0, stream,
                       edges, mask, Vw, qbf, Kbf, w1w, biasw, gkw,
                       ws_m, ws_z, ws_A, ws_O);
    hipLaunchKernelGGL(combine_kernel, dim3(rows/2), dim3(256), 0, stream,
                       rvW2, rvb2, Wo, bo, ws_m, ws_z, ws_A, ws_O, (float*)d_out);
}

// Round 15
// 112.842 us; speedup vs baseline: 1.0411x; 1.0411x over previous
//
#include <hip/hip_runtime.h>
#include <hip/hip_bf16.h>

#define HH 8
#define DKK 32
#define DM 256
#define NN 512
#define DE 40
#define DHID 32
#define CH 128

typedef __attribute__((ext_vector_type(4))) short short4v;
typedef __attribute__((ext_vector_type(8))) short short8v;
typedef __attribute__((ext_vector_type(4))) float f32x4;

__device__ __forceinline__ unsigned short f2bf(float x) {
    union { __hip_bfloat16 h; unsigned short u; } c;
    c.h = __float2bfloat16(x);
    return c.u;
}
__device__ __forceinline__ float bf2f(unsigned short u) {
    return __uint_as_float(((unsigned int)u) << 16);
}
__device__ __forceinline__ float bf_lo(unsigned int u){ return __uint_as_float(u << 16); }
__device__ __forceinline__ float bf_hi(unsigned int u){ return __uint_as_float(u & 0xffff0000u); }
__device__ __forceinline__ unsigned int pack2bf(float a, float b) {
    return (unsigned int)f2bf(a) | ((unsigned int)f2bf(b) << 16);
}
__device__ __forceinline__ short8v ld8(const unsigned short* p) {
    short4v lo = *(const short4v*)p;
    short4v hi = *(const short4v*)(p + 4);
    short8v r;
    r[0]=lo[0]; r[1]=lo[1]; r[2]=lo[2]; r[3]=lo[3];
    r[4]=hi[0]; r[5]=hi[1]; r[6]=hi[2]; r[7]=hi[3];
    return r;
}

// ---------------- projection: one matrix, 4 rows per block. grid = 3*256 ----------------
__global__ __launch_bounds__(256) void proj_kernel(
    const float* __restrict__ query, const float* __restrict__ key_,
    const float* __restrict__ value,
    const float* __restrict__ Wq, const float* __restrict__ bq,
    const float* __restrict__ Wk, const float* __restrict__ bk,
    const float* __restrict__ Wv, const float* __restrict__ bv,
    float* __restrict__ Q, float* __restrict__ K, float* __restrict__ V,
    int grpPerMat)
{
    const int m  = blockIdx.x / grpPerMat;          // 0=q 1=k 2=v
    const int r0 = (blockIdx.x % grpPerMat) * 4;
    const float* x; const float* W; const float* bb; float* dst;
    if (m == 0)      { x = query; W = Wq; bb = bq; dst = Q; }
    else if (m == 1) { x = key_;  W = Wk; bb = bk; dst = K; }
    else             { x = value; W = Wv; bb = bv; dst = V; }
    const int c = threadIdx.x;
    const float b0 = bb[c];
    float a0 = b0, a1 = b0, a2 = b0, a3 = b0;
    for (int k = 0; k < DM; ++k) {
        const float w = W[k*DM + c];
        a0 = fmaf(x[(size_t)(r0+0)*DM + k], w, a0);   // uniform x -> scalar loads
        a1 = fmaf(x[(size_t)(r0+1)*DM + k], w, a1);
        a2 = fmaf(x[(size_t)(r0+2)*DM + k], w, a2);
        a3 = fmaf(x[(size_t)(r0+3)*DM + k], w, a3);
    }
    dst[(size_t)(r0+0)*DM + c] = a0;
    dst[(size_t)(r0+1)*DM + c] = a1;
    dst[(size_t)(r0+2)*DM + c] = a2;
    dst[(size_t)(r0+3)*DM + c] = a3;
}

// ---------------- pre: s1 tiles (0..1023) + prep rows (1024..2047) + w1 (2048) ----------------
__global__ __launch_bounds__(256) void pre_kernel(
    const float* __restrict__ Q, const float* __restrict__ K,
    const float* __restrict__ vvec,
    const float* __restrict__ rkW2, const float* __restrict__ rkb2,
    const float* __restrict__ rkW1, const float* __restrict__ rvW1,
    const float* __restrict__ rkb1, const float* __restrict__ rvb1,
    unsigned short* __restrict__ s1, float* __restrict__ gkw,
    unsigned short* __restrict__ w1w, float* __restrict__ biasw)
{
    const int bid = blockIdx.x;
    const int tid = threadIdx.x;
    __shared__ __align__(16) float sh[2*64*33];

    if (bid < 1024) {
        // ---- s1 tile: s1[b,h,i,j] = inv * q_h(i).k_h(j), bf16 ----
        float (*Qt)[33] = (float(*)[33])sh;
        float (*Kt)[33] = (float(*)[33])(sh + 64*33);
        const int bh = bid >> 6, b = bh >> 3, hh = bh & 7;
        const int bx = bid & 63;
        const int ti = (bx >> 3) * 64, tj = (bx & 7) * 64;
        const int c = tid & 31, r0 = tid >> 5;
#pragma unroll
        for (int s = 0; s < 8; ++s) {
            Qt[r0 + 8*s][c] = Q[(size_t)(b*NN + ti + r0 + 8*s)*DM + hh*DKK + c];
            Kt[r0 + 8*s][c] = K[(size_t)(b*NN + tj + r0 + 8*s)*DM + hh*DKK + c];
        }
        __syncthreads();
        const int tx = tid & 15, ty = tid >> 4;
        float acc[4][4] = {};
#pragma unroll
        for (int k = 0; k < DKK; ++k) {
            float qv[4], kv[4];
#pragma unroll
            for (int u = 0; u < 4; ++u) { qv[u] = Qt[ty*4+u][k]; kv[u] = Kt[tx*4+u][k]; }
#pragma unroll
            for (int ri = 0; ri < 4; ++ri)
#pragma unroll
                for (int cj = 0; cj < 4; ++cj)
                    acc[ri][cj] = fmaf(qv[ri], kv[cj], acc[ri][cj]);
        }
        const float inv = 0.17677669529663687f;
#pragma unroll
        for (int ri = 0; ri < 4; ++ri) {
            ushort4 o;
            o.x = f2bf(acc[ri][0]*inv); o.y = f2bf(acc[ri][1]*inv);
            o.z = f2bf(acc[ri][2]*inv); o.w = f2bf(acc[ri][3]*inv);
            *(ushort4*)(s1 + ((size_t)(b*HH + hh)*NN + ti + ty*4 + ri)*NN + tj + tx*4) = o;
        }
    } else if (bid < 2048) {
        // ---- prep: per-row gK[h,t] (f32), c0K[h] ----
        const int bi = bid - 1024;
        const int h = tid >> 5, l32 = tid & 31;
        const float inv = 0.17677669529663687f;
        float* wf = sh;
        wf[tid] = inv*(Q[(size_t)bi*DM + tid] + K[(size_t)bi*DM + tid]) + vvec[tid];
        __syncthreads();
        float acc = 0.f;
#pragma unroll
        for (int d4 = 0; d4 < DKK/4; ++d4) {
            const float4 w4 = *(const float4*)(rkW2 + (size_t)l32*DM + h*DKK + d4*4);
            const float4 f4 = *(const float4*)(&wf[h*DKK + d4*4]);
            acc = fmaf(w4.x, f4.x, acc); acc = fmaf(w4.y, f4.y, acc);
            acc = fmaf(w4.z, f4.z, acc); acc = fmaf(w4.w, f4.w, acc);
        }
        gkw[(size_t)bi*264 + tid] = acc;
        if (tid < HH) {
            float a2 = 0.f;
#pragma unroll
            for (int d = 0; d < DKK; ++d)
                a2 = fmaf(rkb2[tid*DKK + d], wf[tid*DKK + d], a2);
            gkw[(size_t)bi*264 + 256 + tid] = a2;
        }
    } else {
        // ---- w1: combined W1k|W1v bf16 [64][68] + bias[64] ----
        const int n = tid >> 2, qd = tid & 3;
#pragma unroll
        for (int kk = 0; kk < 17; ++kk) {
            const int k = qd*17 + kk;
            float v = 0.f;
            if (k < DE) v = (n < 32) ? rkW1[k*DHID + n] : rvW1[k*DHID + (n-32)];
            w1w[n*68 + k] = f2bf(v);
        }
        if (tid < 64) biasw[tid] = (tid < 32) ? rkb1[tid] : rvb1[tid-32];
    }
}

// ---------------- chunk kernel: ONE 128-j chunk per block. grid = rows*4 ----------------
// 5 barriers; partials written straight to ws (combine does 16-way sum).
__global__ __launch_bounds__(256, 5) void chunk_kernel(
    const float* __restrict__ edges, const int* __restrict__ mask,
    const float* __restrict__ V,
    const unsigned short* __restrict__ s1u,
    const unsigned short* __restrict__ w1w, const float* __restrict__ biasw,
    const float* __restrict__ gkw,
    float* __restrict__ ws_m, float* __restrict__ ws_z,
    float* __restrict__ ws_A4, float* __restrict__ ws_O4)
{
    const int bid = blockIdx.x;
    const int bi = bid >> 2, cq = bid & 3;   // row, j-quarter
    const int b  = bi >> 9;
    const int i  = bi & 511;
    const int j0 = cq*CH;
    const int tid = threadIdx.x;
    const int h = tid >> 5, l32 = tid & 31;          // softmax mapping
    const int wid = tid >> 6, lane = tid & 63;       // wave mapping (mfma)
    const int g = lane >> 4, q16 = lane & 15;
    const int team = tid >> 6, qq = tid & 63, hq = qq >> 3;  // accO mapping
    const int jj = tid & 127, half = tid >> 7;       // E-load / scores mapping

    // ---- LDS ----
    __shared__ __align__(16) unsigned char uni[17408];
    __shared__ __align__(16) unsigned short W1bf[64*68];
    __shared__ __align__(16) float sc[HH*132];
    __shared__ __align__(16) float gKs[HH*DKK];
    __shared__ float c0Ks[HH];
    __shared__ float bias_l[64];

    unsigned short* E   = (unsigned short*)uni;              // [128][68] bf16
    unsigned short* hvT = (unsigned short*)uni;              // [32][132] bf16 (overlays E)
    unsigned short* hk  = (unsigned short*)(uni + 8448);     // [128][34] bf16
    unsigned short* pb  = (unsigned short*)(uni + 8448);     // [16][132] bf16 (in hk space)

    const size_t ebase = (size_t)b*DE*NN*NN + (size_t)i*NN;

    // ---- prefetch: edges, s1, mask (all independent of LDS) ----
    float ev[20];
    {
        const float* ep = edges + ebase + j0 + jj;
#pragma unroll
        for (int u = 0; u < 20; ++u) ev[u] = ep[(size_t)(half*20+u)*NN*NN];
    }
    unsigned short s1v[4];
    {
        const unsigned short* s1b = s1u + (size_t)b*HH*NN*NN + (size_t)i*NN + j0 + jj;
#pragma unroll
        for (int u = 0; u < 4; ++u) s1v[u] = s1b[(size_t)(half*4+u)*NN*NN];
    }
    const int mk = mask[b*NN + j0 + jj];

    // ---- prologue copies + E pack: ONE barrier ----
    {
        const unsigned int* src = (const unsigned int*)w1w;
        unsigned int* dst = (unsigned int*)W1bf;
#pragma unroll
        for (int u = tid; u < 2176; u += 256) dst[u] = src[u];
        const float* gsrc = gkw + (size_t)bi*264;
        gKs[tid] = gsrc[tid];
        if (tid < HH) c0Ks[tid] = gsrc[256 + tid];
        if (tid < 64) bias_l[tid] = biasw[tid];

        unsigned int* Ed = (unsigned int*)&E[jj*68 + half*20];
#pragma unroll
        for (int u = 0; u < 10; ++u) Ed[u] = pack2bf(ev[2*u], ev[2*u+1]);
        if (half) {
            unsigned int* Ez = (unsigned int*)&E[jj*68 + 40];
#pragma unroll
            for (int z = 0; z < 12; ++z) Ez[z] = 0u;
        }
    }
    __syncthreads();   // B1: E + staging ready

    float biasv[4];
#pragma unroll
    for (int nt = 0; nt < 4; ++nt) biasv[nt] = bias_l[nt*16 + q16];

    // ---- h1 = E @ W1 (+bias) via MFMA: wave owns 32 j rows ----
    f32x4 acc[2][4];
#pragma unroll
    for (int jt = 0; jt < 2; ++jt) {
        const int jn = wid*32 + jt*16 + q16;
        short8v a0 = ld8(&E[jn*68 + g*8]);
        short8v a1 = ld8(&E[jn*68 + 32 + g*8]);
#pragma unroll
        for (int nt = 0; nt < 4; ++nt) {
            const unsigned short* wp = &W1bf[(q16 + nt*16)*68 + g*8];
            f32x4 c;
            c[0] = biasv[nt]; c[1] = biasv[nt]; c[2] = biasv[nt]; c[3] = biasv[nt];
            c = __builtin_amdgcn_mfma_f32_16x16x32_bf16(a0, ld8(wp), c, 0, 0, 0);
            c = __builtin_amdgcn_mfma_f32_16x16x32_bf16(a1, ld8(wp + 32), c, 0, 0, 0);
            acc[jt][nt] = c;
        }
    }
    __syncthreads();   // B2: all E reads done before overwrite

    // ---- leaky + writeback: hk[j][t] and hvT[t][j] ----
#pragma unroll
    for (int jt = 0; jt < 2; ++jt) {
        const int jw = wid*32 + jt*16 + g*4;
#pragma unroll
        for (int nt = 0; nt < 4; ++nt) {
#pragma unroll
            for (int r = 0; r < 4; ++r) {
                float x = acc[jt][nt][r];
                x = x > 0.f ? x : 0.1f*x;
                const unsigned short us = f2bf(x);
                const int n = nt*16 + q16;
                if (n < 32) hk[(jw+r)*34 + n] = us;
                else        hvT[(n-32)*132 + (jw+r)] = us;
            }
        }
    }
    __syncthreads();   // B3: hk/hvT ready

    // ---- scores: s2 (gK . h1k) + prefetched s1 + mask ----
    {
        unsigned int hku[16];
#pragma unroll
        for (int d = 0; d < 16; ++d) hku[d] = *(const unsigned int*)&hk[jj*34 + 2*d];
        float racc[4];
#pragma unroll
        for (int u = 0; u < 4; ++u) racc[u] = c0Ks[half*4 + u];
#pragma unroll
        for (int d = 0; d < 16; ++d) {
            const float lo = bf_lo(hku[d]), hi = bf_hi(hku[d]);
#pragma unroll
            for (int u = 0; u < 4; ++u) {
                const int hh = half*4 + u;
                racc[u] = fmaf(gKs[hh*DKK + 2*d],     lo, racc[u]);
                racc[u] = fmaf(gKs[hh*DKK + 2*d + 1], hi, racc[u]);
            }
        }
#pragma unroll
        for (int u = 0; u < 4; ++u) {
            const int hh = half*4 + u;
            float r = racc[u] + bf2f(s1v[u]);
            if (mk == 0) r = -1e12f;
            sc[hh*132 + jj] = r;
        }
    }
    __syncthreads();   // B4: sc ready

    // ---- local softmax (head h per 32-lane group), publish p bf16, emit m/Z ----
    {
        float sv[4];
        float mc = -3e38f;
#pragma unroll
        for (int k = 0; k < 4; ++k) { sv[k] = sc[h*132 + l32 + 32*k]; mc = fmaxf(mc, sv[k]); }
#pragma unroll
        for (int off = 16; off; off >>= 1) mc = fmaxf(mc, __shfl_xor(mc, off, 32));
        float zc = 0.f;
#pragma unroll
        for (int k = 0; k < 4; ++k) {
            const float e = __expf(sv[k] - mc);
            pb[h*132 + l32 + 32*k] = f2bf(e);
            zc += e;
        }
#pragma unroll
        for (int off = 16; off; off >>= 1) zc += __shfl_xor(zc, off, 32);
        if (l32 == 0) {
            ws_m[(size_t)bid*8 + h] = mc;
            ws_z[(size_t)bid*8 + h] = zc;
        }
    }
    __syncthreads();   // B5: pb visible to all waves

    // ---- accA via MFMA (wave = K-quarter) ----
    f32x4 ca0 = {0.f,0.f,0.f,0.f}, ca1 = {0.f,0.f,0.f,0.f};
    {
        short8v pA = ld8(&pb[q16*132 + wid*32 + g*8]);
        short8v b0 = ld8(&hvT[q16*132 + wid*32 + g*8]);
        short8v b1 = ld8(&hvT[(16+q16)*132 + wid*32 + g*8]);
        ca0 = __builtin_amdgcn_mfma_f32_16x16x32_bf16(pA, b0, ca0, 0, 0, 0);
        ca1 = __builtin_amdgcn_mfma_f32_16x16x32_bf16(pA, b1, ca1, 0, 0, 0);
    }
    // ---- accO: coalesced scalar loop (channels qq*4..+3, j = j0 + team + 4*it) ----
    float aO0 = 0.f, aO1 = 0.f, aO2 = 0.f, aO3 = 0.f;
    {
        const float* vrow = V + (size_t)b*NN*DM + (size_t)(j0 + team)*DM + qq*4;
        const unsigned short* ph = pb + hq*132 + team;
#pragma unroll 4
        for (int it = 0; it < 32; ++it) {
            const float p = bf2f(ph[4*it]);
            const float4 v4 = *(const float4*)(vrow + (size_t)it*4*DM);
            aO0 = fmaf(p, v4.x, aO0); aO1 = fmaf(p, v4.y, aO1);
            aO2 = fmaf(p, v4.z, aO2); aO3 = fmaf(p, v4.w, aO3);
        }
    }

    // ---- direct ws writes: per-wave A partials, per-team O partials (no barriers) ----
    if (g < 2) {
        float* pa = ws_A4 + ((size_t)bid*4 + wid)*256;
#pragma unroll
        for (int r = 0; r < 4; ++r) {
            const int hrow = g*4 + r;
            pa[hrow*32 + q16]      = ca0[r];
            pa[hrow*32 + 16 + q16] = ca1[r];
        }
    }
    *(float4*)(ws_O4 + ((size_t)bid*4 + team)*256 + qq*4) = make_float4(aO0, aO1, aO2, aO3);
}

// ---------------- combine: 4-way flash merge over 16-way partials, o2, Wo. 2 rows/block ----------------
__global__ __launch_bounds__(256) void combine_kernel(
    const float* __restrict__ rvW2, const float* __restrict__ rvb2,
    const float* __restrict__ Wo, const float* __restrict__ bo,
    const float* __restrict__ ws_m, const float* __restrict__ ws_z,
    const float* __restrict__ ws_A4, const float* __restrict__ ws_O4,
    float* __restrict__ out)
{
    const int bi0 = blockIdx.x * 2;
    const int tid = threadIdx.x;
    const int h = tid >> 5;
    __shared__ float A_l[2][DM], o_l[2][DM];
    __shared__ float wqs[2][4][HH], rzs[2][HH];

    if (tid < 16) {
        const int r = tid >> 3, hh = tid & 7;
        const int bi = bi0 + r;
        float mv[4], zv[4];
#pragma unroll
        for (int q = 0; q < 4; ++q) {
            mv[q] = ws_m[(size_t)(bi*4+q)*8 + hh];
            zv[q] = ws_z[(size_t)(bi*4+q)*8 + hh];
        }
        const float mm = fmaxf(fmaxf(mv[0], mv[1]), fmaxf(mv[2], mv[3]));
        float zt = 0.f;
#pragma unroll
        for (int q = 0; q < 4; ++q) {
            const float w = __expf(mv[q] - mm);
            wqs[r][q][hh] = w;
            zt = fmaf(zv[q], w, zt);
        }
        rzs[r][hh] = 1.f / zt;
    }
    __syncthreads();

    float o1v[2];
#pragma unroll
    for (int r = 0; r < 2; ++r) {
        const int bi = bi0 + r;
        const float rz = rzs[r][h];
        float A = 0.f, o1 = 0.f;
#pragma unroll
        for (int q = 0; q < 4; ++q) {
            const float w = wqs[r][q][h];
            const float* pa = ws_A4 + ((size_t)(bi*4+q))*1024 + tid;
            const float* po = ws_O4 + ((size_t)(bi*4+q))*1024 + tid;
            A  = fmaf(w, (pa[0]+pa[256]) + (pa[512]+pa[768]), A);
            o1 = fmaf(w, (po[0]+po[256]) + (po[512]+po[768]), o1);
        }
        A_l[r][tid] = A * rz;
        o1v[r] = o1 * rz;
    }
    __syncthreads();

#pragma unroll
    for (int r = 0; r < 2; ++r) {
        float o2 = rvb2[tid];
#pragma unroll
        for (int t = 0; t < DHID; ++t)
            o2 = fmaf(A_l[r][h*DKK + t], rvW2[(size_t)t*DM + tid], o2);
        o_l[r][tid] = o1v[r] + o2;
    }
    __syncthreads();

    float acc0 = bo[tid], acc1 = acc0;
#pragma unroll 4
    for (int k = 0; k < DM; ++k) {
        const float w = Wo[(size_t)k*DM + tid];
        acc0 = fmaf(o_l[0][k], w, acc0);
        acc1 = fmaf(o_l[1][k], w, acc1);
    }
    out[(size_t)(bi0+0)*DM + tid] = acc0;
    out[(size_t)(bi0+1)*DM + tid] = acc1;
}

extern "C" void kernel_launch(void* const* d_in, const int* in_sizes, int n_in,
                              void* d_out, int out_size, void* d_ws, size_t ws_size,
                              hipStream_t stream) {
    const float* query = (const float*)d_in[0];
    const float* key_  = (const float*)d_in[1];
    const float* value = (const float*)d_in[2];
    const float* edges = (const float*)d_in[3];
    const int*   mask  = (const int*)d_in[4];
    const float* Wq = (const float*)d_in[5];
    const float* bq = (const float*)d_in[6];
    const float* Wk = (const float*)d_in[7];
    const float* bk = (const float*)d_in[8];
    const float* Wv = (const float*)d_in[9];
    const float* bv = (const float*)d_in[10];
    const float* Wo = (const float*)d_in[11];
    const float* bo = (const float*)d_in[12];
    const float* rkW1 = (const float*)d_in[13];
    const float* rkb1 = (const float*)d_in[14];
    const float* rkW2 = (const float*)d_in[15];
    const float* rkb2 = (const float*)d_in[16];
    const float* rvW1 = (const float*)d_in[17];
    const float* rvb1 = (const float*)d_in[18];
    const float* rvW2 = (const float*)d_in[19];
    const float* rvb2 = (const float*)d_in[20];
    // d_in[21] (u) is softmax-invariant -> unused
    const float* vvec = (const float*)d_in[22];

    const int rows = in_sizes[0] / DM;   // b*n = 1024
    const int nchunk = rows * 4;         // 4096

    float* Qw    = (float*)d_ws;
    float* Kw    = Qw + (size_t)rows*DM;
    float* Vw    = Kw + (size_t)rows*DM;
    float* gkw   = Vw + (size_t)rows*DM;                      // rows*264
    float* biasw = gkw + (size_t)rows*264;                    // 64
    float* ws_m  = biasw + 64;
    float* ws_z  = ws_m + (size_t)nchunk*8;
    float* ws_A4 = ws_z + (size_t)nchunk*8;                   // nchunk*4*256
    float* ws_O4 = ws_A4 + (size_t)nchunk*1024;               // nchunk*4*256
    unsigned short* s1u = (unsigned short*)(ws_O4 + (size_t)nchunk*1024); // 2*8*512*512
    unsigned short* w1w = s1u + (size_t)2*HH*NN*NN;           // 64*68

    hipLaunchKernelGGL(proj_kernel, dim3(3*rows/4), dim3(256), 0, stream,
                       query, key_, value, Wq, bq, Wk, bk, Wv, bv,
                       Qw, Kw, Vw, rows/4);
    hipLaunchKernelGGL(pre_kernel, dim3(2*rows + 1), dim3(256), 0, stream,
                       Qw, Kw, vvec, rkW2, rkb2, rkW1, rvW1, rkb1, rvb1,
                       s1u, gkw, w1w, biasw);
    hipLaunchKernelGGL(chunk_kernel, dim3(nchunk), dim3(256), 0, stream,
                       edges, mask, Vw, s1u, w1w, biasw, gkw,
                       ws_m, ws_z, ws_A4, ws_O4);
    hipLaunchKernelGGL(combine_kernel, dim3(rows/2), dim3(256), 0, stream,
                       rvW2, rvb2, Wo, bo, ws_m, ws_z, ws_A4, ws_O4, (float*)d_out);
}

// Round 16
// 96.760 us; speedup vs baseline: 1.2141x; 1.1662x over previous
//
#include <hip/hip_runtime.h>
#include <hip/hip_bf16.h>

#define HH 8
#define DKK 32
#define DM 256
#define NN 512
#define DE 40
#define DHID 32
#define CH 128

typedef __attribute__((ext_vector_type(4))) short short4v;
typedef __attribute__((ext_vector_type(8))) short short8v;
typedef __attribute__((ext_vector_type(4))) float f32x4;

__device__ __forceinline__ unsigned short f2bf(float x) {
    union { __hip_bfloat16 h; unsigned short u; } c;
    c.h = __float2bfloat16(x);
    return c.u;
}
__device__ __forceinline__ float bf2f(unsigned short u) {
    return __uint_as_float(((unsigned int)u) << 16);
}
__device__ __forceinline__ float bf_lo(unsigned int u){ return __uint_as_float(u << 16); }
__device__ __forceinline__ float bf_hi(unsigned int u){ return __uint_as_float(u & 0xffff0000u); }
__device__ __forceinline__ unsigned int pack2bf(float a, float b) {
    return (unsigned int)f2bf(a) | ((unsigned int)f2bf(b) << 16);
}
__device__ __forceinline__ short8v ld8(const unsigned short* p) {
    short4v lo = *(const short4v*)p;
    short4v hi = *(const short4v*)(p + 4);
    short8v r;
    r[0]=lo[0]; r[1]=lo[1]; r[2]=lo[2]; r[3]=lo[3];
    r[4]=hi[0]; r[5]=hi[1]; r[6]=hi[2]; r[7]=hi[3];
    return r;
}

// ---------------- projection: one matrix, 4 rows per block. grid = 3*256 ----------------
__global__ __launch_bounds__(256) void proj_kernel(
    const float* __restrict__ query, const float* __restrict__ key_,
    const float* __restrict__ value,
    const float* __restrict__ Wq, const float* __restrict__ bq,
    const float* __restrict__ Wk, const float* __restrict__ bk,
    const float* __restrict__ Wv, const float* __restrict__ bv,
    float* __restrict__ Q, float* __restrict__ K, float* __restrict__ V,
    int grpPerMat)
{
    const int m  = blockIdx.x / grpPerMat;          // 0=q 1=k 2=v
    const int r0 = (blockIdx.x % grpPerMat) * 4;
    const float* x; const float* W; const float* bb; float* dst;
    if (m == 0)      { x = query; W = Wq; bb = bq; dst = Q; }
    else if (m == 1) { x = key_;  W = Wk; bb = bk; dst = K; }
    else             { x = value; W = Wv; bb = bv; dst = V; }
    const int c = threadIdx.x;
    const float b0 = bb[c];
    float a0 = b0, a1 = b0, a2 = b0, a3 = b0;
    for (int k = 0; k < DM; ++k) {
        const float w = W[k*DM + c];
        a0 = fmaf(x[(size_t)(r0+0)*DM + k], w, a0);   // uniform x -> scalar loads
        a1 = fmaf(x[(size_t)(r0+1)*DM + k], w, a1);
        a2 = fmaf(x[(size_t)(r0+2)*DM + k], w, a2);
        a3 = fmaf(x[(size_t)(r0+3)*DM + k], w, a3);
    }
    dst[(size_t)(r0+0)*DM + c] = a0;
    dst[(size_t)(r0+1)*DM + c] = a1;
    dst[(size_t)(r0+2)*DM + c] = a2;
    dst[(size_t)(r0+3)*DM + c] = a3;
}

// ---------------- pre: s1 tiles (0..1023) + prep rows (1024..2047) + w1 (2048) ----------------
__global__ __launch_bounds__(256) void pre_kernel(
    const float* __restrict__ Q, const float* __restrict__ K,
    const float* __restrict__ vvec,
    const float* __restrict__ rkW2, const float* __restrict__ rkb2,
    const float* __restrict__ rkW1, const float* __restrict__ rvW1,
    const float* __restrict__ rkb1, const float* __restrict__ rvb1,
    unsigned short* __restrict__ s1, float* __restrict__ gkw,
    unsigned short* __restrict__ w1w, float* __restrict__ biasw)
{
    const int bid = blockIdx.x;
    const int tid = threadIdx.x;
    __shared__ __align__(16) float sh[2*64*33];

    if (bid < 1024) {
        // ---- s1 tile: s1[b,h,i,j] = inv * q_h(i).k_h(j), bf16 ----
        float (*Qt)[33] = (float(*)[33])sh;
        float (*Kt)[33] = (float(*)[33])(sh + 64*33);
        const int bh = bid >> 6, b = bh >> 3, hh = bh & 7;
        const int bx = bid & 63;
        const int ti = (bx >> 3) * 64, tj = (bx & 7) * 64;
        const int c = tid & 31, r0 = tid >> 5;
#pragma unroll
        for (int s = 0; s < 8; ++s) {
            Qt[r0 + 8*s][c] = Q[(size_t)(b*NN + ti + r0 + 8*s)*DM + hh*DKK + c];
            Kt[r0 + 8*s][c] = K[(size_t)(b*NN + tj + r0 + 8*s)*DM + hh*DKK + c];
        }
        __syncthreads();
        const int tx = tid & 15, ty = tid >> 4;
        float acc[4][4] = {};
#pragma unroll
        for (int k = 0; k < DKK; ++k) {
            float qv[4], kv[4];
#pragma unroll
            for (int u = 0; u < 4; ++u) { qv[u] = Qt[ty*4+u][k]; kv[u] = Kt[tx*4+u][k]; }
#pragma unroll
            for (int ri = 0; ri < 4; ++ri)
#pragma unroll
                for (int cj = 0; cj < 4; ++cj)
                    acc[ri][cj] = fmaf(qv[ri], kv[cj], acc[ri][cj]);
        }
        const float inv = 0.17677669529663687f;
#pragma unroll
        for (int ri = 0; ri < 4; ++ri) {
            ushort4 o;
            o.x = f2bf(acc[ri][0]*inv); o.y = f2bf(acc[ri][1]*inv);
            o.z = f2bf(acc[ri][2]*inv); o.w = f2bf(acc[ri][3]*inv);
            *(ushort4*)(s1 + ((size_t)(b*HH + hh)*NN + ti + ty*4 + ri)*NN + tj + tx*4) = o;
        }
    } else if (bid < 2048) {
        // ---- prep: per-row gK[h,t] (f32), c0K[h] ----
        const int bi = bid - 1024;
        const int h = tid >> 5, l32 = tid & 31;
        const float inv = 0.17677669529663687f;
        float* wf = sh;
        wf[tid] = inv*(Q[(size_t)bi*DM + tid] + K[(size_t)bi*DM + tid]) + vvec[tid];
        __syncthreads();
        float acc = 0.f;
#pragma unroll
        for (int d4 = 0; d4 < DKK/4; ++d4) {
            const float4 w4 = *(const float4*)(rkW2 + (size_t)l32*DM + h*DKK + d4*4);
            const float4 f4 = *(const float4*)(&wf[h*DKK + d4*4]);
            acc = fmaf(w4.x, f4.x, acc); acc = fmaf(w4.y, f4.y, acc);
            acc = fmaf(w4.z, f4.z, acc); acc = fmaf(w4.w, f4.w, acc);
        }
        gkw[(size_t)bi*264 + tid] = acc;
        if (tid < HH) {
            float a2 = 0.f;
#pragma unroll
            for (int d = 0; d < DKK; ++d)
                a2 = fmaf(rkb2[tid*DKK + d], wf[tid*DKK + d], a2);
            gkw[(size_t)bi*264 + 256 + tid] = a2;
        }
    } else {
        // ---- w1: combined W1k|W1v bf16 [64][68] + bias[64] ----
        const int n = tid >> 2, qd = tid & 3;
#pragma unroll
        for (int kk = 0; kk < 17; ++kk) {
            const int k = qd*17 + kk;
            float v = 0.f;
            if (k < DE) v = (n < 32) ? rkW1[k*DHID + n] : rvW1[k*DHID + (n-32)];
            w1w[n*68 + k] = f2bf(v);
        }
        if (tid < 64) biasw[tid] = (tid < 32) ? rkb1[tid] : rvb1[tid-32];
    }
}

// ---------------- chunk kernel: ONE 128-j chunk per block. grid = rows*4 ----------------
// r11 structure; W1/bias direct from global (no LDS copy) -> ~22.7 KB LDS, 6+ blocks/CU.
__global__ __launch_bounds__(256, 6) void chunk_kernel(
    const float* __restrict__ edges, const int* __restrict__ mask,
    const float* __restrict__ V,
    const unsigned short* __restrict__ s1u,
    const unsigned short* __restrict__ w1w, const float* __restrict__ biasw,
    const float* __restrict__ gkw,
    float* __restrict__ ws_m, float* __restrict__ ws_z,
    float* __restrict__ ws_A, float* __restrict__ ws_O)
{
    const int bid = blockIdx.x;
    const int bi = bid >> 2, cq = bid & 3;   // row, j-quarter
    const int b  = bi >> 9;
    const int i  = bi & 511;
    const int j0 = cq*CH;
    const int tid = threadIdx.x;
    const int h = tid >> 5, l32 = tid & 31;          // softmax mapping
    const int wid = tid >> 6, lane = tid & 63;       // wave mapping (mfma)
    const int g = lane >> 4, q16 = lane & 15;
    const int team = tid >> 6, qq = tid & 63, hq = qq >> 3;  // accO mapping
    const int jj = tid & 127, half = tid >> 7;       // E-load / scores mapping

    // ---- LDS ----
    __shared__ __align__(16) unsigned char uni[17408];
    __shared__ __align__(16) float sc[HH*132];
    __shared__ __align__(16) float gKs[HH*DKK];
    __shared__ float c0Ks[HH];

    unsigned short* E   = (unsigned short*)uni;              // [128][68] bf16
    unsigned short* hvT = (unsigned short*)uni;              // [32][132] bf16 (overlays E)
    unsigned short* hk  = (unsigned short*)(uni + 8448);     // [128][34] bf16
    unsigned short* pb  = (unsigned short*)(uni + 8448);     // [16][132] bf16 (in hk space)
    float* paccA = (float*)uni;                              // [4][256] epilogue
    float* po    = (float*)(uni + 4096);                     // [4][256] epilogue

    const size_t ebase = (size_t)b*DE*NN*NN + (size_t)i*NN;

    // ---- prefetch: edges, s1, mask, bias (all LDS-independent) ----
    float ev[20];
    {
        const float* ep = edges + ebase + j0 + jj;
#pragma unroll
        for (int u = 0; u < 20; ++u) ev[u] = ep[(size_t)(half*20+u)*NN*NN];
    }
    unsigned short s1v[4];
    {
        const unsigned short* s1b = s1u + (size_t)b*HH*NN*NN + (size_t)i*NN + j0 + jj;
#pragma unroll
        for (int u = 0; u < 4; ++u) s1v[u] = s1b[(size_t)(half*4+u)*NN*NN];
    }
    const int mk = mask[b*NN + j0 + jj];
    float biasv[4];
#pragma unroll
    for (int nt = 0; nt < 4; ++nt) biasv[nt] = biasw[nt*16 + q16];

    // ---- prologue copies (gK) + E pack: ONE barrier ----
    {
        const float* gsrc = gkw + (size_t)bi*264;
        gKs[tid] = gsrc[tid];
        if (tid < HH) c0Ks[tid] = gsrc[256 + tid];

        unsigned int* Ed = (unsigned int*)&E[jj*68 + half*20];
#pragma unroll
        for (int u = 0; u < 10; ++u) Ed[u] = pack2bf(ev[2*u], ev[2*u+1]);
        if (half) {
            unsigned int* Ez = (unsigned int*)&E[jj*68 + 40];
#pragma unroll
            for (int z = 0; z < 12; ++z) Ez[z] = 0u;
        }
    }
    __syncthreads();   // B1: E + gKs ready

    // ---- h1 = E @ W1 (+bias) via MFMA; W1 fragments direct from global (L1-hot) ----
    f32x4 acc[2][4];
#pragma unroll
    for (int jt = 0; jt < 2; ++jt) {
        const int jn = wid*32 + jt*16 + q16;
        short8v a0 = ld8(&E[jn*68 + g*8]);
        short8v a1 = ld8(&E[jn*68 + 32 + g*8]);
#pragma unroll
        for (int nt = 0; nt < 4; ++nt) {
            const unsigned short* wp = w1w + (q16 + nt*16)*68 + g*8;
            f32x4 c;
            c[0] = biasv[nt]; c[1] = biasv[nt]; c[2] = biasv[nt]; c[3] = biasv[nt];
            c = __builtin_amdgcn_mfma_f32_16x16x32_bf16(a0, ld8(wp), c, 0, 0, 0);
            c = __builtin_amdgcn_mfma_f32_16x16x32_bf16(a1, ld8(wp + 32), c, 0, 0, 0);
            acc[jt][nt] = c;
        }
    }
    __syncthreads();   // B2: all E reads done before overwrite

    // ---- leaky + writeback: hk[j][t] and hvT[t][j] ----
#pragma unroll
    for (int jt = 0; jt < 2; ++jt) {
        const int jw = wid*32 + jt*16 + g*4;
#pragma unroll
        for (int nt = 0; nt < 4; ++nt) {
#pragma unroll
            for (int r = 0; r < 4; ++r) {
                float x = acc[jt][nt][r];
                x = x > 0.f ? x : 0.1f*x;
                const unsigned short us = f2bf(x);
                const int n = nt*16 + q16;
                if (n < 32) hk[(jw+r)*34 + n] = us;
                else        hvT[(n-32)*132 + (jw+r)] = us;
            }
        }
    }
    __syncthreads();   // B3: hk/hvT ready

    // ---- scores: s2 (gK . h1k) + prefetched s1 + mask ----
    {
        unsigned int hku[16];
#pragma unroll
        for (int d = 0; d < 16; ++d) hku[d] = *(const unsigned int*)&hk[jj*34 + 2*d];
        float racc[4];
#pragma unroll
        for (int u = 0; u < 4; ++u) racc[u] = c0Ks[half*4 + u];
#pragma unroll
        for (int d = 0; d < 16; ++d) {
            const float lo = bf_lo(hku[d]), hi = bf_hi(hku[d]);
#pragma unroll
            for (int u = 0; u < 4; ++u) {
                const int hh = half*4 + u;
                racc[u] = fmaf(gKs[hh*DKK + 2*d],     lo, racc[u]);
                racc[u] = fmaf(gKs[hh*DKK + 2*d + 1], hi, racc[u]);
            }
        }
#pragma unroll
        for (int u = 0; u < 4; ++u) {
            const int hh = half*4 + u;
            float r = racc[u] + bf2f(s1v[u]);
            if (mk == 0) r = -1e12f;
            sc[hh*132 + jj] = r;
        }
    }
    __syncthreads();   // B4: sc ready

    // ---- local softmax (head h per 32-lane group), publish p bf16, emit m/Z ----
    {
        float sv[4];
        float mc = -3e38f;
#pragma unroll
        for (int k = 0; k < 4; ++k) { sv[k] = sc[h*132 + l32 + 32*k]; mc = fmaxf(mc, sv[k]); }
#pragma unroll
        for (int off = 16; off; off >>= 1) mc = fmaxf(mc, __shfl_xor(mc, off, 32));
        float zc = 0.f;
#pragma unroll
        for (int k = 0; k < 4; ++k) {
            const float e = __expf(sv[k] - mc);
            pb[h*132 + l32 + 32*k] = f2bf(e);
            zc += e;
        }
#pragma unroll
        for (int off = 16; off; off >>= 1) zc += __shfl_xor(zc, off, 32);
        if (l32 == 0) {
            ws_m[(size_t)bid*8 + h] = mc;
            ws_z[(size_t)bid*8 + h] = zc;
        }
    }
    __syncthreads();   // B5: pb visible to all waves

    // ---- accA via MFMA (wave = K-quarter) ----
    f32x4 ca0 = {0.f,0.f,0.f,0.f}, ca1 = {0.f,0.f,0.f,0.f};
    {
        short8v pA = ld8(&pb[q16*132 + wid*32 + g*8]);
        short8v b0 = ld8(&hvT[q16*132 + wid*32 + g*8]);
        short8v b1 = ld8(&hvT[(16+q16)*132 + wid*32 + g*8]);
        ca0 = __builtin_amdgcn_mfma_f32_16x16x32_bf16(pA, b0, ca0, 0, 0, 0);
        ca1 = __builtin_amdgcn_mfma_f32_16x16x32_bf16(pA, b1, ca1, 0, 0, 0);
    }
    // ---- accO: coalesced scalar loop (channels qq*4..+3, j = j0 + team + 4*it) ----
    float aO0 = 0.f, aO1 = 0.f, aO2 = 0.f, aO3 = 0.f;
    {
        const float* vrow = V + (size_t)b*NN*DM + (size_t)(j0 + team)*DM + qq*4;
        const unsigned short* ph = pb + hq*132 + team;
#pragma unroll 4
        for (int it = 0; it < 32; ++it) {
            const float p = bf2f(ph[4*it]);
            const float4 v4 = *(const float4*)(vrow + (size_t)it*4*DM);
            aO0 = fmaf(p, v4.x, aO0); aO1 = fmaf(p, v4.y, aO1);
            aO2 = fmaf(p, v4.z, aO2); aO3 = fmaf(p, v4.w, aO3);
        }
    }
    __syncthreads();   // B6: pb/hvT consumed; epilogue overlays uni

    // ---- epilogue: reduce wave partials in LDS, emit raw (A, O) ----
    if (g < 2) {
#pragma unroll
        for (int r = 0; r < 4; ++r) {
            const int hrow = g*4 + r;
            paccA[wid*256 + hrow*32 + q16]      = ca0[r];
            paccA[wid*256 + hrow*32 + 16 + q16] = ca1[r];
        }
    }
    *(float4*)(po + team*256 + qq*4) = make_float4(aO0, aO1, aO2, aO3);
    __syncthreads();   // B7

    ws_A[(size_t)bid*256 + tid] = paccA[tid] + paccA[256+tid] + paccA[512+tid] + paccA[768+tid];
    ws_O[(size_t)bid*256 + tid] = po[tid] + po[256+tid] + po[512+tid] + po[768+tid];
}

// ---------------- combine: 4-way flash merge, o2, Wo epilogue. 2 rows per block ----------------
__global__ __launch_bounds__(256) void combine_kernel(
    const float* __restrict__ rvW2, const float* __restrict__ rvb2,
    const float* __restrict__ Wo, const float* __restrict__ bo,
    const float* __restrict__ ws_m, const float* __restrict__ ws_z,
    const float* __restrict__ ws_A, const float* __restrict__ ws_O,
    float* __restrict__ out)
{
    const int bi0 = blockIdx.x * 2;
    const int tid = threadIdx.x;
    const int h = tid >> 5;
    __shared__ float A_l[2][DM], o_l[2][DM];
    __shared__ float wqs[2][4][HH], rzs[2][HH];

    if (tid < 16) {
        const int r = tid >> 3, hh = tid & 7;
        const int bi = bi0 + r;
        float mv[4], zv[4];
#pragma unroll
        for (int q = 0; q < 4; ++q) {
            mv[q] = ws_m[(size_t)(bi*4+q)*8 + hh];
            zv[q] = ws_z[(size_t)(bi*4+q)*8 + hh];
        }
        const float mm = fmaxf(fmaxf(mv[0], mv[1]), fmaxf(mv[2], mv[3]));
        float zt = 0.f;
#pragma unroll
        for (int q = 0; q < 4; ++q) {
            const float w = __expf(mv[q] - mm);
            wqs[r][q][hh] = w;
            zt = fmaf(zv[q], w, zt);
        }
        rzs[r][hh] = 1.f / zt;
    }
    __syncthreads();

    float o1v[2];
#pragma unroll
    for (int r = 0; r < 2; ++r) {
        const int bi = bi0 + r;
        const float rz = rzs[r][h];
        float A = 0.f, o1 = 0.f;
#pragma unroll
        for (int q = 0; q < 4; ++q) {
            const float w = wqs[r][q][h];
            A  = fmaf(w, ws_A[(size_t)(bi*4+q)*256 + tid], A);
            o1 = fmaf(w, ws_O[(size_t)(bi*4+q)*256 + tid], o1);
        }
        A_l[r][tid] = A * rz;
        o1v[r] = o1 * rz;
    }
    __syncthreads();

#pragma unroll
    for (int r = 0; r < 2; ++r) {
        float o2 = rvb2[tid];
#pragma unroll
        for (int t = 0; t < DHID; ++t)
            o2 = fmaf(A_l[r][h*DKK + t], rvW2[(size_t)t*DM + tid], o2);
        o_l[r][tid] = o1v[r] + o2;
    }
    __syncthreads();

    float acc0 = bo[tid], acc1 = acc0;
#pragma unroll 4
    for (int k = 0; k < DM; ++k) {
        const float w = Wo[(size_t)k*DM + tid];
        acc0 = fmaf(o_l[0][k], w, acc0);
        acc1 = fmaf(o_l[1][k], w, acc1);
    }
    out[(size_t)(bi0+0)*DM + tid] = acc0;
    out[(size_t)(bi0+1)*DM + tid] = acc1;
}

extern "C" void kernel_launch(void* const* d_in, const int* in_sizes, int n_in,
                              void* d_out, int out_size, void* d_ws, size_t ws_size,
                              hipStream_t stream) {
    const float* query = (const float*)d_in[0];
    const float* key_  = (const float*)d_in[1];
    const float* value = (const float*)d_in[2];
    const float* edges = (const float*)d_in[3];
    const int*   mask  = (const int*)d_in[4];
    const float* Wq = (const float*)d_in[5];
    const float* bq = (const float*)d_in[6];
    const float* Wk = (const float*)d_in[7];
    const float* bk = (const float*)d_in[8];
    const float* Wv = (const float*)d_in[9];
    const float* bv = (const float*)d_in[10];
    const float* Wo = (const float*)d_in[11];
    const float* bo = (const float*)d_in[12];
    const float* rkW1 = (const float*)d_in[13];
    const float* rkb1 = (const float*)d_in[14];
    const float* rkW2 = (const float*)d_in[15];
    const float* rkb2 = (const float*)d_in[16];
    const float* rvW1 = (const float*)d_in[17];
    const float* rvb1 = (const float*)d_in[18];
    const float* rvW2 = (const float*)d_in[19];
    const float* rvb2 = (const float*)d_in[20];
    // d_in[21] (u) is softmax-invariant -> unused
    const float* vvec = (const float*)d_in[22];

    const int rows = in_sizes[0] / DM;   // b*n = 1024
    const int nchunk = rows * 4;         // 4096

    float* Qw    = (float*)d_ws;
    float* Kw    = Qw + (size_t)rows*DM;
    float* Vw    = Kw + (size_t)rows*DM;
    float* gkw   = Vw + (size_t)rows*DM;                      // rows*264
    float* biasw = gkw + (size_t)rows*264;                    // 64
    float* ws_m  = biasw + 64;
    float* ws_z  = ws_m + (size_t)nchunk*8;
    float* ws_A  = ws_z + (size_t)nchunk*8;                   // nchunk*256
    float* ws_O  = ws_A + (size_t)nchunk*256;                 // nchunk*256
    unsigned short* s1u = (unsigned short*)(ws_O + (size_t)nchunk*256); // 2*8*512*512
    unsigned short* w1w = s1u + (size_t)2*HH*NN*NN;           // 64*68

    hipLaunchKernelGGL(proj_kernel, dim3(3*rows/4), dim3(256), 0, stream,
                       query, key_, value, Wq, bq, Wk, bk, Wv, bv,
                       Qw, Kw, Vw, rows/4);
    hipLaunchKernelGGL(pre_kernel, dim3(2*rows + 1), dim3(256), 0, stream,
                       Qw, Kw, vvec, rkW2, rkb2, rkW1, rvW1, rkb1, rvb1,
                       s1u, gkw, w1w, biasw);
    hipLaunchKernelGGL(chunk_kernel, dim3(nchunk), dim3(256), 0, stream,
                       edges, mask, Vw, s1u, w1w, biasw, gkw,
                       ws_m, ws_z, ws_A, ws_O);
    hipLaunchKernelGGL(combine_kernel, dim3(rows/2), dim3(256), 0, stream,
                       rvW2, rvb2, Wo, bo, ws_m, ws_z, ws_A, ws_O, (float*)d_out);
}